// Round 3
// baseline (777.914 us; speedup 1.0000x reference)
//
#include <hip/hip_runtime.h>
#include <stdint.h>

#define HW 65536

typedef __attribute__((ext_vector_type(8))) short short8;
typedef __attribute__((ext_vector_type(4))) float f32x4;
typedef unsigned short u16;

struct __align__(8) us4 { u16 x, y, z, w; };
struct __align__(16) us8 { us4 lo, hi; };

__device__ __forceinline__ u16 f2bf(float f) {
  union { float f; uint32_t u; } v; v.f = f;
  uint32_t r = v.u + 0x7FFFu + ((v.u >> 16) & 1u);   // round-to-nearest-even
  return (u16)(r >> 16);
}

__device__ __forceinline__ us4 pack4(float a, float b, float c, float d) {
  us4 o; o.x = f2bf(a); o.y = f2bf(b); o.z = f2bf(c); o.w = f2bf(d); return o;
}

// Reorder OIHW fp32 weights -> bf16 [tap][cigroup][co][8], zero-padded in ci and co.
__device__ __forceinline__ void reorder_one(int idx, const float* __restrict__ src,
                                            u16* __restrict__ dst, int CO, int CI,
                                            int COp, int Cp) {
  int cc = idx & 7;
  int t = idx >> 3;
  int co = t % COp;
  int u = t / COp;
  int cgn = Cp >> 3;
  int cg = u % cgn;
  int tap = u / cgn;
  int ci = cg * 8 + cc;
  float v = 0.f;
  if (co < CO && ci < CI) v = src[(co * CI + ci) * 9 + tap];
  dst[idx] = f2bf(v);
}

// fusion_in for one pixel p: bf16 channel-blocked [n][y][cg=4][x][8ch], 32ch (24 valid)
__device__ __forceinline__ void fusion_in_one(int p, const float* __restrict__ ft0,
                                              const float* __restrict__ ft1,
                                              const float* __restrict__ gup,
                                              const float* __restrict__ ca,
                                              const float* __restrict__ cb,
                                              u16* __restrict__ fin) {
  const int n = p >> 16;
  const int pp = p & 65535;
  const float* b0 = ft0 + (size_t)n * 64 * HW + pp;
  const float* b1 = ft1 + (size_t)n * 64 * HW + pp;
  const float a = ca[0], bb = cb[0];
  u16* base = fin + ((size_t)(n * 256 + (pp >> 8)) * 4 * 256 + (pp & 255)) * 8;
  us8 o;
#pragma unroll
  for (int cg = 0; cg < 2; ++cg) {
    float v[8];
#pragma unroll
    for (int r = 0; r < 8; ++r) {
      const int ch = cg * 8 + r;
      v[r] = fabsf(b1[ch * HW] - b0[ch * HW]);
    }
    o.lo = pack4(v[0], v[1], v[2], v[3]);
    o.hi = pack4(v[4], v[5], v[6], v[7]);
    *(us8*)(base + cg * 2048) = o;
  }
  const float* gu = gup + (size_t)n * 4 * HW + pp;
  o.lo = pack4(gu[0], gu[HW], gu[2 * HW], gu[3 * HW]);
  o.hi = pack4(fminf(fmaxf(b1[0 * HW], 0.f), 1.f) * a + bb,
               fminf(fmaxf(b1[1 * HW], 0.f), 1.f) * a + bb,
               fminf(fmaxf(b1[2 * HW], 0.f), 1.f) * a + bb,
               fminf(fmaxf(b1[3 * HW], 0.f), 1.f) * a + bb);
  *(us8*)(base + 2 * 2048) = o;
  const us4 zz = {0, 0, 0, 0};
  o.lo = zz; o.hi = zz;
  *(us8*)(base + 3 * 2048) = o;
}

// One launch: all 6 weight reorders + ZROW zero + fusion_in.
// Segments (threads): 18432,36864,9216,73728,36864,36864 | 32768 | 262144 -> 506880.
__global__ void prep_k(const float* __restrict__ s1, const float* __restrict__ s2,
                       const float* __restrict__ s3, const float* __restrict__ s4,
                       const float* __restrict__ s5, const float* __restrict__ s6,
                       u16* __restrict__ d1, u16* __restrict__ d2, u16* __restrict__ d3,
                       u16* __restrict__ d4, u16* __restrict__ d5, u16* __restrict__ d6,
                       u16* __restrict__ zrow,
                       const float* __restrict__ ft0, const float* __restrict__ ft1,
                       const float* __restrict__ gup, const float* __restrict__ ca,
                       const float* __restrict__ cb, u16* __restrict__ fin) {
  int idx = blockIdx.x * 256 + threadIdx.x;
  if (idx < 18432) { reorder_one(idx, s1, d1, 64, 24, 64, 32); return; }
  idx -= 18432;
  if (idx < 36864) { reorder_one(idx, s2, d2, 64, 64, 64, 64); return; }
  idx -= 36864;
  if (idx < 9216)  { reorder_one(idx, s3, d3, 4, 64, 16, 64); return; }
  idx -= 9216;
  if (idx < 73728) { reorder_one(idx, s4, d4, 64, 100, 64, 128); return; }
  idx -= 73728;
  if (idx < 36864) { reorder_one(idx, s5, d5, 64, 64, 64, 64); return; }
  idx -= 36864;
  if (idx < 36864) { reorder_one(idx, s6, d6, 64, 64, 64, 64); return; }
  idx -= 36864;
  if (idx < 32768) { zrow[idx] = 0; return; }
  idx -= 32768;
  fusion_in_one(idx, ft0, ft1, gup, ca, cb, fin);
}

// Implicit-GEMM 3x3 conv, pad=1, input bf16 channel-blocked [y][CIN/8][x][8]
// (CIN mult of 32). Block = 2 output rows x 256 px, 512 threads.
// SINGLE-buffered LDS staging (66.3 KB) -> 2 blocks/CU (16 waves/CU); inter-block
// overlap covers barrier/stage latency instead of intra-block double-buffering.
// Stage: 4 input rows x 32ci via global_load_lds(16B), each wave = contiguous 1KB.
// Weights in registers: taps 0-4 preloaded before the barrier, taps 5-8 rolling.
// OMODE 0: bf16 channel-blocked out (64ch) + bias + relu
// OMODE 1: fp32 NCHW out (64ch) + bias            (denoise_out)
// OMODE 2: gamma (sigmoid, 4ch fp32 NCHW) + FUSED fusion_post epilogue
template <int CIN, int MT, int OMODE>
__global__ __launch_bounds__(512, 4) void conv3_k(
    const u16* __restrict__ in, const u16* __restrict__ wr,
    const float* __restrict__ bias, const u16* __restrict__ zrow,
    u16* __restrict__ obf, float* __restrict__ of32,
    const float* __restrict__ ft0, const float* __restrict__ ft1,
    const float* __restrict__ dd, const float* __restrict__ ca,
    const float* __restrict__ cb, float* __restrict__ fo_out,
    float* __restrict__ si_out, u16* __restrict__ din) {
  constexpr int M = MT * 16;
  constexpr int NCH = CIN / 32;
  constexpr int NREG = 16;      // 4 rows x 4 k-groups
  constexpr int RSTR = 259;     // 258 slots + 1 pad
  __shared__ __align__(16) u16 Blds[NREG * RSTR * 8];   // 66.3 KB -> 2 blocks/CU
  const int tid = threadIdx.x;
  const int w = tid >> 6;
  const int lane = tid & 63;
  const int l15 = lane & 15;
  const int quad = lane >> 4;
  const int yo = w >> 2;        // which of the 2 output rows
  const int wq = w & 3;         // 64-px quarter

  // XCD swizzle: consecutive y-tiles share an XCD for halo L2 reuse
  const int b = blockIdx.x;
  const int i = b >> 3;
  const int n = i >> 4;
  const int ytile = ((b & 7) << 4) + (i & 15);
  const int y0 = ytile * 2;

  f32x4 acc[MT][4];
#pragma unroll
  for (int mt = 0; mt < MT; ++mt)
#pragma unroll
    for (int nt = 0; nt < 4; ++nt) acc[mt][nt] = (f32x4){0.f, 0.f, 0.f, 0.f};

  const u16* inb = in + (size_t)n * HW * CIN;
  const u16* rp[4];
#pragma unroll
  for (int r = 0; r < 4; ++r) {
    const int y2 = y0 + r - 1;
    rp[r] = (y2 >= 0 && y2 < 256) ? (inb + (size_t)y2 * 256 * CIN) : zrow;
  }
  // zero x-halo slots (0 and 257) of all 16 regions; persists across chunks
  if (tid < 32) {
    const int reg = tid >> 1;
    const int sl = (tid & 1) * 257;
    *(float4*)&Blds[((size_t)reg * RSTR + sl) * 8] = (float4){0.f, 0.f, 0.f, 0.f};
  }

  auto stage = [&](int c) {
#pragma unroll
    for (int it = 0; it < 8; ++it) {
      const int reg = it * 2 + (tid >> 8);
      const int r = reg >> 2;
      const int g = reg & 3;
      const int slot = tid & 255;
      // channel-blocked: group (c*4+g) of row r, pixel 'slot' -> contiguous 16B
      const u16* gp = rp[r] + ((size_t)(c * 4 + g) * 256 + slot) * 8;
      u16* lp = &Blds[((size_t)reg * RSTR + 1 + slot) * 8];
      __builtin_amdgcn_global_load_lds(
          (const __attribute__((address_space(1))) void*)gp,
          (__attribute__((address_space(3))) void*)lp, 16, 0, 0);
    }
  };

  stage(0);

  for (int c = 0; c < NCH; ++c) {
    const int cg0 = c * 4;
    short8 aw[6][MT];
    // taps 0-4 weight loads issued before the barrier (drain together with stage)
#pragma unroll
    for (int t = 0; t < 5; ++t)
#pragma unroll
      for (int mt = 0; mt < MT; ++mt)
        aw[t][mt] = *(const short8*)(wr +
            (size_t)((t * (CIN / 8) + cg0 + quad) * M + mt * 16 + l15) * 8);
    __syncthreads();   // stage(c) landed in LDS
#pragma unroll
    for (int tap = 0; tap < 9; ++tap) {
      const int ky = tap / 3;
      const int kx = tap - ky * 3;
      if (tap < 4) {   // rolling prefetch of taps 5..8
        const int t2 = tap + 5;
        const int sl = t2 % 6;
#pragma unroll
        for (int mt = 0; mt < MT; ++mt)
          aw[sl][mt] = *(const short8*)(wr +
              (size_t)((t2 * (CIN / 8) + cg0 + quad) * M + mt * 16 + l15) * 8);
      }
      const int slcur = tap % 6;
      short8 bfrag[4];
#pragma unroll
      for (int nt = 0; nt < 4; ++nt)
        bfrag[nt] = *(const short8*)&Blds[(((size_t)(yo + ky) * 4 + quad) * RSTR +
                                           wq * 64 + nt * 16 + l15 + kx) * 8];
#pragma unroll
      for (int mt = 0; mt < MT; ++mt)
#pragma unroll
        for (int nt = 0; nt < 4; ++nt)
          acc[mt][nt] = __builtin_amdgcn_mfma_f32_16x16x32_bf16(aw[slcur][mt], bfrag[nt],
                                                                acc[mt][nt], 0, 0, 0);
    }
    if (c + 1 < NCH) {
      __syncthreads();   // all reads of the buffer done; safe to re-stage
      stage(c + 1);
    }
  }

  const int y = y0 + yo;
  // Epilogue. C/D: col(pix)=lane&15, row(co within tile)=quad*4+reg
  if (OMODE == 0) {
    // channel-blocked out: row base + ((co/8)*256 + pix)*8 + (co&7)
    u16* ob = obf + ((size_t)n * 256 + y) * 256 * 64;
#pragma unroll
    for (int mt = 0; mt < MT; ++mt) {
      const int co = mt * 16 + quad * 4;
      const float b0 = bias[co], b1 = bias[co + 1], b2 = bias[co + 2], b3 = bias[co + 3];
#pragma unroll
      for (int nt = 0; nt < 4; ++nt) {
        const int pix = (wq * 4 + nt) * 16 + l15;
        f32x4 cc = acc[mt][nt];
        us4 o = pack4(fmaxf(cc[0] + b0, 0.f), fmaxf(cc[1] + b1, 0.f),
                      fmaxf(cc[2] + b2, 0.f), fmaxf(cc[3] + b3, 0.f));
        *(us4*)(ob + (size_t)((co >> 3) * 256 + pix) * 8 + (co & 7)) = o;
      }
    }
  } else if (OMODE == 1) {
#pragma unroll
    for (int mt = 0; mt < MT; ++mt) {
#pragma unroll
      for (int nt = 0; nt < 4; ++nt) {
        const int pix = (wq * 4 + nt) * 16 + l15;
        f32x4 cc = acc[mt][nt];
#pragma unroll
        for (int r = 0; r < 4; ++r) {
          const int co = mt * 16 + quad * 4 + r;
          of32[((size_t)n * 64 + co) * HW + y * 256 + pix] = cc[r] + bias[co];
        }
      }
    }
  } else {
    // --- OMODE 2: gamma + fused fusion_post ---
    __syncthreads();          // all K-loop LDS reads done; Blds reusable
    float* glds = (float*)Blds;   // [2][256][4] fp32 gamma
    if (quad == 0) {
#pragma unroll
      for (int nt = 0; nt < 4; ++nt) {
        const int pix = (wq * 4 + nt) * 16 + l15;
        f32x4 cc = acc[0][nt];
        float gv[4];
#pragma unroll
        for (int r = 0; r < 4; ++r) {
          gv[r] = 1.f / (1.f + expf(-(cc[r] + bias[r])));
          of32[((size_t)n * 4 + r) * HW + y * 256 + pix] = gv[r];
        }
        *(f32x4*)&glds[((size_t)yo * 256 + pix) * 4] =
            (f32x4){gv[0], gv[1], gv[2], gv[3]};
      }
    }
    __syncthreads();
    // each of the 512 threads owns pixel (n, yy, xx) of the block's 2x256 tile
    const int yo2 = tid >> 8;
    const int xx = tid & 255;
    const int yy = y0 + yo2;
    const int pp = yy * 256 + xx;
    const float* b0 = ft0 + (size_t)n * 64 * HW + pp;
    const float* b1 = ft1 + (size_t)n * 64 * HW + pp;
    float* fo = fo_out + (size_t)n * 64 * HW + pp;
    const float a = ca[0], bb = cb[0];
    float g[4];
    {
      f32x4 gv = *(const f32x4*)&glds[((size_t)yo2 * 256 + xx) * 4];
      g[0] = gv[0]; g[1] = gv[1]; g[2] = gv[2]; g[3] = gv[3];
    }
    u16* dbase = din + ((size_t)(n * 256 + yy) * 16 * 256 + xx) * 8;
    us8 o;
    // groups 0-7: fusion_out ch 0-63 (also written fp32 NCHW)
#pragma unroll
    for (int cg = 0; cg < 8; ++cg) {
      const float gg = g[cg >> 1];
      float v[8];
#pragma unroll
      for (int r = 0; r < 8; ++r) {
        const int ch = cg * 8 + r;
        const float f0 = b0[ch * HW];
        const float f1 = b1[ch * HW];
        const float x = f0 + gg * (f1 - f0);
        fo[ch * HW] = x;
        v[r] = x;
      }
      o.lo = pack4(v[0], v[1], v[2], v[3]);
      o.hi = pack4(v[4], v[5], v[6], v[7]);
      *(us8*)(dbase + cg * 2048) = o;
    }
    // groups 8-9: ll1 = ft1 ch 0-15
#pragma unroll
    for (int cg = 0; cg < 2; ++cg) {
      o.lo = pack4(b1[(cg * 8 + 0) * HW], b1[(cg * 8 + 1) * HW],
                   b1[(cg * 8 + 2) * HW], b1[(cg * 8 + 3) * HW]);
      o.hi = pack4(b1[(cg * 8 + 4) * HW], b1[(cg * 8 + 5) * HW],
                   b1[(cg * 8 + 6) * HW], b1[(cg * 8 + 7) * HW]);
      *(us8*)(dbase + (8 + cg) * 2048) = o;
    }
    // groups 10-11: denoise_down ch 0-15
    const float* dn = dd + (size_t)n * 16 * HW + pp;
#pragma unroll
    for (int cg = 0; cg < 2; ++cg) {
      o.lo = pack4(dn[(cg * 8 + 0) * HW], dn[(cg * 8 + 1) * HW],
                   dn[(cg * 8 + 2) * HW], dn[(cg * 8 + 3) * HW]);
      o.hi = pack4(dn[(cg * 8 + 4) * HW], dn[(cg * 8 + 5) * HW],
                   dn[(cg * 8 + 6) * HW], dn[(cg * 8 + 7) * HW]);
      *(us8*)(dbase + (10 + cg) * 2048) = o;
    }
    // sigma (fp32 NCHW out + group 12 lo)
    float s[4];
#pragma unroll
    for (int j = 0; j < 4; ++j) {
      const float f0 = b0[j * HW], f1 = b1[j * HW];
      const float sl0 = fminf(fmaxf(f0, 0.f), 1.f) * a + bb;
      const float sl1 = fminf(fmaxf(f1, 0.f), 1.f) * a + bb;
      const float om = 1.f - g[j];
      s[j] = om * om * sl0 + g[j] * g[j] * sl1;
      si_out[((size_t)n * 4 + j) * HW + pp] = s[j];
    }
    const us4 zz = {0, 0, 0, 0};
    o.lo = pack4(s[0], s[1], s[2], s[3]);
    o.hi = zz;
    *(us8*)(dbase + 12 * 2048) = o;
    // groups 13-15: zeros
    o.lo = zz;
#pragma unroll
    for (int cg = 13; cg < 16; ++cg) *(us8*)(dbase + cg * 2048) = o;
  }
}

extern "C" void kernel_launch(void* const* d_in, const int* in_sizes, int n_in,
                              void* d_out, int out_size, void* d_ws, size_t ws_size,
                              hipStream_t stream) {
  (void)in_sizes; (void)n_in; (void)out_size; (void)ws_size;
  const float* ft0 = (const float*)d_in[0];
  const float* ft1 = (const float*)d_in[1];
  const float* gup = (const float*)d_in[2];
  const float* dd  = (const float*)d_in[3];
  const float* ca  = (const float*)d_in[4];
  const float* cb  = (const float*)d_in[5];
  const float* fw1 = (const float*)d_in[6];  const float* fb1 = (const float*)d_in[7];
  const float* fw2 = (const float*)d_in[8];  const float* fb2 = (const float*)d_in[9];
  const float* fw3 = (const float*)d_in[10]; const float* fb3 = (const float*)d_in[11];
  const float* dw1 = (const float*)d_in[12]; const float* db1 = (const float*)d_in[13];
  const float* dw2 = (const float*)d_in[14]; const float* db2 = (const float*)d_in[15];
  const float* dw3 = (const float*)d_in[16]; const float* db3 = (const float*)d_in[17];

  float* out = (float*)d_out;
  float* fo_out = out;                               // fusion_out  4*64*HW
  float* do_out = out + (size_t)4 * 64 * HW;         // denoise_out 4*64*HW
  float* ga_out = out + (size_t)8 * 64 * HW;         // gamma       4*4*HW
  float* si_out = ga_out + (size_t)4 * 4 * HW;       // sigma       4*4*HW

  char* ws = (char*)d_ws;
  u16* WR1 = (u16*)(ws);
  u16* WR2 = (u16*)(ws + 36864);
  u16* WR3 = (u16*)(ws + 110592);
  u16* WD1 = (u16*)(ws + 129024);
  u16* WD2 = (u16*)(ws + 276480);
  u16* WD3 = (u16*)(ws + 350208);
  u16* ZROW = (u16*)(ws + 425984);                   // 64 KB zeros
  u16* FIN = (u16*)(ws + (1 << 20));                 // 16 MB
  u16* H1  = (u16*)(ws + 17825792);                  // 32 MB
  u16* H2  = (u16*)(ws + 51380224);                  // 32 MB
  u16* DIN = (u16*)do_out;                           // 64 MB, dead until dconv3

  dim3 blk(256);
  // merged: 6 weight reorders + ZROW zero + fusion_in in one launch (506880 threads)
  prep_k<<<1980, blk, 0, stream>>>(fw1, fw2, fw3, dw1, dw2, dw3,
                                   WR1, WR2, WR3, WD1, WD2, WD3, ZROW,
                                   ft0, ft1, gup, ca, cb, FIN);

  dim3 cblk(512);
  conv3_k<32, 4, 0><<<512, cblk, 0, stream>>>(FIN, WR1, fb1, ZROW, H1, nullptr,
      nullptr, nullptr, nullptr, nullptr, nullptr, nullptr, nullptr, nullptr);
  conv3_k<64, 4, 0><<<512, cblk, 0, stream>>>(H1, WR2, fb2, ZROW, H2, nullptr,
      nullptr, nullptr, nullptr, nullptr, nullptr, nullptr, nullptr, nullptr);
  // gamma conv with fused fusion_post: writes gamma, fusion_out, sigma, DIN
  conv3_k<64, 1, 2><<<512, cblk, 0, stream>>>(H2, WR3, fb3, ZROW, nullptr, ga_out,
      ft0, ft1, dd, ca, cb, fo_out, si_out, DIN);
  conv3_k<128, 4, 0><<<512, cblk, 0, stream>>>(DIN, WD1, db1, ZROW, H1, nullptr,
      nullptr, nullptr, nullptr, nullptr, nullptr, nullptr, nullptr, nullptr);
  conv3_k<64, 4, 0><<<512, cblk, 0, stream>>>(H1, WD2, db2, ZROW, H2, nullptr,
      nullptr, nullptr, nullptr, nullptr, nullptr, nullptr, nullptr, nullptr);
  conv3_k<64, 4, 1><<<512, cblk, 0, stream>>>(H2, WD3, db3, ZROW, nullptr, do_out,
      nullptr, nullptr, nullptr, nullptr, nullptr, nullptr, nullptr, nullptr);
}

// Round 6
// 440.820 us; speedup vs baseline: 1.7647x; 1.7647x over previous
//
#include <hip/hip_runtime.h>
#include <stdint.h>

#define HW 65536

typedef __attribute__((ext_vector_type(8))) short short8;
typedef __attribute__((ext_vector_type(4))) float f32x4;
typedef unsigned short u16;

struct __align__(8) us4 { u16 x, y, z, w; };
struct __align__(16) us8 { us4 lo, hi; };

__device__ __forceinline__ u16 f2bf(float f) {
  union { float f; uint32_t u; } v; v.f = f;
  uint32_t r = v.u + 0x7FFFu + ((v.u >> 16) & 1u);   // round-to-nearest-even
  return (u16)(r >> 16);
}

__device__ __forceinline__ us4 pack4(float a, float b, float c, float d) {
  us4 o; o.x = f2bf(a); o.y = f2bf(b); o.z = f2bf(c); o.w = f2bf(d); return o;
}

// Reorder OIHW fp32 weights -> bf16 [tap][cigroup][co][8], zero-padded in ci and co.
__device__ __forceinline__ void reorder_one(int idx, const float* __restrict__ src,
                                            u16* __restrict__ dst, int CO, int CI,
                                            int COp, int Cp) {
  int cc = idx & 7;
  int t = idx >> 3;
  int co = t % COp;
  int u = t / COp;
  int cgn = Cp >> 3;
  int cg = u % cgn;
  int tap = u / cgn;
  int ci = cg * 8 + cc;
  float v = 0.f;
  if (co < CO && ci < CI) v = src[(co * CI + ci) * 9 + tap];
  dst[idx] = f2bf(v);
}

// fusion_in for one pixel p: bf16 channel-blocked [n][y][cg=4][x][8ch], 32ch (24 valid)
__device__ __forceinline__ void fusion_in_one(int p, const float* __restrict__ ft0,
                                              const float* __restrict__ ft1,
                                              const float* __restrict__ gup,
                                              const float* __restrict__ ca,
                                              const float* __restrict__ cb,
                                              u16* __restrict__ fin) {
  const int n = p >> 16;
  const int pp = p & 65535;
  const float* b0 = ft0 + (size_t)n * 64 * HW + pp;
  const float* b1 = ft1 + (size_t)n * 64 * HW + pp;
  const float a = ca[0], bb = cb[0];
  u16* base = fin + ((size_t)(n * 256 + (pp >> 8)) * 4 * 256 + (pp & 255)) * 8;
  us8 o;
#pragma unroll
  for (int cg = 0; cg < 2; ++cg) {
    float v[8];
#pragma unroll
    for (int r = 0; r < 8; ++r) {
      const int ch = cg * 8 + r;
      v[r] = fabsf(b1[ch * HW] - b0[ch * HW]);
    }
    o.lo = pack4(v[0], v[1], v[2], v[3]);
    o.hi = pack4(v[4], v[5], v[6], v[7]);
    *(us8*)(base + cg * 2048) = o;
  }
  const float* gu = gup + (size_t)n * 4 * HW + pp;
  o.lo = pack4(gu[0], gu[HW], gu[2 * HW], gu[3 * HW]);
  o.hi = pack4(fminf(fmaxf(b1[0 * HW], 0.f), 1.f) * a + bb,
               fminf(fmaxf(b1[1 * HW], 0.f), 1.f) * a + bb,
               fminf(fmaxf(b1[2 * HW], 0.f), 1.f) * a + bb,
               fminf(fmaxf(b1[3 * HW], 0.f), 1.f) * a + bb);
  *(us8*)(base + 2 * 2048) = o;
  const us4 zz = {0, 0, 0, 0};
  o.lo = zz; o.hi = zz;
  *(us8*)(base + 3 * 2048) = o;
}

// One launch: all 6 weight reorders + ZROW zero + fusion_in.
// Segments (threads): 18432,36864,9216,73728,36864,36864 | 32768 | 262144 -> 506880.
__global__ void prep_k(const float* __restrict__ s1, const float* __restrict__ s2,
                       const float* __restrict__ s3, const float* __restrict__ s4,
                       const float* __restrict__ s5, const float* __restrict__ s6,
                       u16* __restrict__ d1, u16* __restrict__ d2, u16* __restrict__ d3,
                       u16* __restrict__ d4, u16* __restrict__ d5, u16* __restrict__ d6,
                       u16* __restrict__ zrow,
                       const float* __restrict__ ft0, const float* __restrict__ ft1,
                       const float* __restrict__ gup, const float* __restrict__ ca,
                       const float* __restrict__ cb, u16* __restrict__ fin) {
  int idx = blockIdx.x * 256 + threadIdx.x;
  if (idx < 18432) { reorder_one(idx, s1, d1, 64, 24, 64, 32); return; }
  idx -= 18432;
  if (idx < 36864) { reorder_one(idx, s2, d2, 64, 64, 64, 64); return; }
  idx -= 36864;
  if (idx < 9216)  { reorder_one(idx, s3, d3, 4, 64, 16, 64); return; }
  idx -= 9216;
  if (idx < 73728) { reorder_one(idx, s4, d4, 64, 100, 64, 128); return; }
  idx -= 73728;
  if (idx < 36864) { reorder_one(idx, s5, d5, 64, 64, 64, 64); return; }
  idx -= 36864;
  if (idx < 36864) { reorder_one(idx, s6, d6, 64, 64, 64, 64); return; }
  idx -= 36864;
  if (idx < 32768) { zrow[idx] = 0; return; }
  idx -= 32768;
  fusion_in_one(idx, ft0, ft1, gup, ca, cb, fin);
}

// Implicit-GEMM 3x3 conv, pad=1, input bf16 channel-blocked [y][CIN/8][x][8]
// (CIN mult of 32). Block = 2 output rows x 256 px x (MT*16) out-channels,
// 512 threads. COB = # of co-blocks (grid = 512*COB); paired co-blocks are
// consecutive on the same XCD so their shared input staging hits L2.
// SINGLE-buffered LDS staging (66.3 KB) + __launch_bounds__(512,2): cap 128
// unified VGPRs -> 2 blocks/CU (16 waves/CU). MT=2 fits this cap without
// spills (acc 32 + aw 48 + bfrag 16 + addressing); MT=4 did NOT (round-3
// spill catastrophe: VGPR capped 64, ~750 MB scratch traffic per dispatch).
// Stage: 4 input rows x 32ci via global_load_lds(16B), each wave = contiguous 1KB.
// OMODE 0: bf16 channel-blocked out + bias + relu
// OMODE 1: fp32 NCHW out + bias                   (denoise_out)
// OMODE 2: gamma (sigmoid, 4ch fp32 NCHW) + FUSED fusion_post epilogue
template <int CIN, int MT, int OMODE, int COB>
__global__ __launch_bounds__(512, 2) void conv3_k(
    const u16* __restrict__ in, const u16* __restrict__ wr,
    const float* __restrict__ bias, const u16* __restrict__ zrow,
    u16* __restrict__ obf, float* __restrict__ of32,
    const float* __restrict__ ft0, const float* __restrict__ ft1,
    const float* __restrict__ dd, const float* __restrict__ ca,
    const float* __restrict__ cb, float* __restrict__ fo_out,
    float* __restrict__ si_out, u16* __restrict__ din) {
  constexpr int M = MT * 16 * COB;   // weight row length (= padded CO)
  constexpr int NCH = CIN / 32;
  constexpr int NREG = 16;      // 4 rows x 4 k-groups
  constexpr int RSTR = 259;     // 258 slots + 1 pad
  __shared__ __align__(16) u16 Blds[NREG * RSTR * 8];   // 66.3 KB -> 2 blocks/CU
  const int tid = threadIdx.x;
  const int w = tid >> 6;
  const int lane = tid & 63;
  const int l15 = lane & 15;
  const int quad = lane >> 4;
  const int yo = w >> 2;        // which of the 2 output rows
  const int wq = w & 3;         // 64-px quarter

  // XCD swizzle: consecutive y-tiles (and co-pairs) share an XCD for L2 reuse
  const int b = blockIdx.x;
  const int i2 = b >> 3;
  const int cob = (COB == 2) ? (i2 & 1) : 0;
  const int i = (COB == 2) ? (i2 >> 1) : i2;
  const int n = i >> 4;
  const int ytile = ((b & 7) << 4) + (i & 15);
  const int y0 = ytile * 2;
  const int co0 = cob * MT * 16;

  f32x4 acc[MT][4];
#pragma unroll
  for (int mt = 0; mt < MT; ++mt)
#pragma unroll
    for (int nt = 0; nt < 4; ++nt) acc[mt][nt] = (f32x4){0.f, 0.f, 0.f, 0.f};

  const u16* inb = in + (size_t)n * HW * CIN;
  const u16* rp[4];
#pragma unroll
  for (int r = 0; r < 4; ++r) {
    const int y2 = y0 + r - 1;
    rp[r] = (y2 >= 0 && y2 < 256) ? (inb + (size_t)y2 * 256 * CIN) : zrow;
  }
  // zero x-halo slots (0 and 257) of all 16 regions; persists across chunks
  if (tid < 32) {
    const int reg = tid >> 1;
    const int sl = (tid & 1) * 257;
    *(float4*)&Blds[((size_t)reg * RSTR + sl) * 8] = (float4){0.f, 0.f, 0.f, 0.f};
  }

  auto stage = [&](int c) {
#pragma unroll
    for (int it = 0; it < 8; ++it) {
      const int reg = it * 2 + (tid >> 8);
      const int r = reg >> 2;
      const int g = reg & 3;
      const int slot = tid & 255;
      // channel-blocked: group (c*4+g) of row r, pixel 'slot' -> contiguous 16B
      const u16* gp = rp[r] + ((size_t)(c * 4 + g) * 256 + slot) * 8;
      u16* lp = &Blds[((size_t)reg * RSTR + 1 + slot) * 8];
      __builtin_amdgcn_global_load_lds(
          (const __attribute__((address_space(1))) void*)gp,
          (__attribute__((address_space(3))) void*)lp, 16, 0, 0);
    }
  };

  stage(0);

  for (int c = 0; c < NCH; ++c) {
    const int cg0 = c * 4;
    short8 aw[6][MT];
    // taps 0-4 weight loads issued before the barrier (drain together with stage)
#pragma unroll
    for (int t = 0; t < 5; ++t)
#pragma unroll
      for (int mt = 0; mt < MT; ++mt)
        aw[t][mt] = *(const short8*)(wr +
            (size_t)((t * (CIN / 8) + cg0 + quad) * M + co0 + mt * 16 + l15) * 8);
    __syncthreads();   // stage(c) landed in LDS
#pragma unroll
    for (int tap = 0; tap < 9; ++tap) {
      const int ky = tap / 3;
      const int kx = tap - ky * 3;
      if (tap < 4) {   // rolling prefetch of taps 5..8
        const int t2 = tap + 5;
        const int sl = t2 % 6;
#pragma unroll
        for (int mt = 0; mt < MT; ++mt)
          aw[sl][mt] = *(const short8*)(wr +
              (size_t)((t2 * (CIN / 8) + cg0 + quad) * M + co0 + mt * 16 + l15) * 8);
      }
      const int slcur = tap % 6;
      short8 bfrag[4];
#pragma unroll
      for (int nt = 0; nt < 4; ++nt)
        bfrag[nt] = *(const short8*)&Blds[(((size_t)(yo + ky) * 4 + quad) * RSTR +
                                           wq * 64 + nt * 16 + l15 + kx) * 8];
#pragma unroll
      for (int mt = 0; mt < MT; ++mt)
#pragma unroll
        for (int nt = 0; nt < 4; ++nt)
          acc[mt][nt] = __builtin_amdgcn_mfma_f32_16x16x32_bf16(aw[slcur][mt], bfrag[nt],
                                                                acc[mt][nt], 0, 0, 0);
    }
    if (c + 1 < NCH) {
      __syncthreads();   // all reads of the buffer done; safe to re-stage
      stage(c + 1);
    }
  }

  const int y = y0 + yo;
  // Epilogue. C/D: col(pix)=lane&15, row(co within tile)=quad*4+reg
  if (OMODE == 0) {
    // channel-blocked out: row base + ((co/8)*256 + pix)*8 + (co&7)
    u16* ob = obf + ((size_t)n * 256 + y) * 256 * 64;
#pragma unroll
    for (int mt = 0; mt < MT; ++mt) {
      const int co = co0 + mt * 16 + quad * 4;
      const float b0 = bias[co], b1 = bias[co + 1], b2 = bias[co + 2], b3 = bias[co + 3];
#pragma unroll
      for (int nt = 0; nt < 4; ++nt) {
        const int pix = (wq * 4 + nt) * 16 + l15;
        f32x4 cc = acc[mt][nt];
        us4 o = pack4(fmaxf(cc[0] + b0, 0.f), fmaxf(cc[1] + b1, 0.f),
                      fmaxf(cc[2] + b2, 0.f), fmaxf(cc[3] + b3, 0.f));
        *(us4*)(ob + (size_t)((co >> 3) * 256 + pix) * 8 + (co & 7)) = o;
      }
    }
  } else if (OMODE == 1) {
#pragma unroll
    for (int mt = 0; mt < MT; ++mt) {
#pragma unroll
      for (int nt = 0; nt < 4; ++nt) {
        const int pix = (wq * 4 + nt) * 16 + l15;
        f32x4 cc = acc[mt][nt];
#pragma unroll
        for (int r = 0; r < 4; ++r) {
          const int co = co0 + mt * 16 + quad * 4 + r;
          of32[((size_t)n * 64 + co) * HW + y * 256 + pix] = cc[r] + bias[co];
        }
      }
    }
  } else {
    // --- OMODE 2: gamma + fused fusion_post ---
    __syncthreads();          // all K-loop LDS reads done; Blds reusable
    float* glds = (float*)Blds;   // [2][256][4] fp32 gamma
    if (quad == 0) {
#pragma unroll
      for (int nt = 0; nt < 4; ++nt) {
        const int pix = (wq * 4 + nt) * 16 + l15;
        f32x4 cc = acc[0][nt];
        float gv[4];
#pragma unroll
        for (int r = 0; r < 4; ++r) {
          gv[r] = 1.f / (1.f + expf(-(cc[r] + bias[r])));
          of32[((size_t)n * 4 + r) * HW + y * 256 + pix] = gv[r];
        }
        *(f32x4*)&glds[((size_t)yo * 256 + pix) * 4] =
            (f32x4){gv[0], gv[1], gv[2], gv[3]};
      }
    }
    __syncthreads();
    // each of the 512 threads owns pixel (n, yy, xx) of the block's 2x256 tile
    const int yo2 = tid >> 8;
    const int xx = tid & 255;
    const int yy = y0 + yo2;
    const int pp = yy * 256 + xx;
    const float* b0 = ft0 + (size_t)n * 64 * HW + pp;
    const float* b1 = ft1 + (size_t)n * 64 * HW + pp;
    float* fo = fo_out + (size_t)n * 64 * HW + pp;
    const float a = ca[0], bb = cb[0];
    float g[4];
    {
      f32x4 gv = *(const f32x4*)&glds[((size_t)yo2 * 256 + xx) * 4];
      g[0] = gv[0]; g[1] = gv[1]; g[2] = gv[2]; g[3] = gv[3];
    }
    u16* dbase = din + ((size_t)(n * 256 + yy) * 16 * 256 + xx) * 8;
    us8 o;
    // groups 0-7: fusion_out ch 0-63 (also written fp32 NCHW)
#pragma unroll
    for (int cg = 0; cg < 8; ++cg) {
      const float gg = g[cg >> 1];
      float v[8];
#pragma unroll
      for (int r = 0; r < 8; ++r) {
        const int ch = cg * 8 + r;
        const float f0 = b0[ch * HW];
        const float f1 = b1[ch * HW];
        const float x = f0 + gg * (f1 - f0);
        fo[ch * HW] = x;
        v[r] = x;
      }
      o.lo = pack4(v[0], v[1], v[2], v[3]);
      o.hi = pack4(v[4], v[5], v[6], v[7]);
      *(us8*)(dbase + cg * 2048) = o;
    }
    // groups 8-9: ll1 = ft1 ch 0-15
#pragma unroll
    for (int cg = 0; cg < 2; ++cg) {
      o.lo = pack4(b1[(cg * 8 + 0) * HW], b1[(cg * 8 + 1) * HW],
                   b1[(cg * 8 + 2) * HW], b1[(cg * 8 + 3) * HW]);
      o.hi = pack4(b1[(cg * 8 + 4) * HW], b1[(cg * 8 + 5) * HW],
                   b1[(cg * 8 + 6) * HW], b1[(cg * 8 + 7) * HW]);
      *(us8*)(dbase + (8 + cg) * 2048) = o;
    }
    // groups 10-11: denoise_down ch 0-15
    const float* dn = dd + (size_t)n * 16 * HW + pp;
#pragma unroll
    for (int cg = 0; cg < 2; ++cg) {
      o.lo = pack4(dn[(cg * 8 + 0) * HW], dn[(cg * 8 + 1) * HW],
                   dn[(cg * 8 + 2) * HW], dn[(cg * 8 + 3) * HW]);
      o.hi = pack4(dn[(cg * 8 + 4) * HW], dn[(cg * 8 + 5) * HW],
                   dn[(cg * 8 + 6) * HW], dn[(cg * 8 + 7) * HW]);
      *(us8*)(dbase + (10 + cg) * 2048) = o;
    }
    // sigma (fp32 NCHW out + group 12 lo)
    float s[4];
#pragma unroll
    for (int j = 0; j < 4; ++j) {
      const float f0 = b0[j * HW], f1 = b1[j * HW];
      const float sl0 = fminf(fmaxf(f0, 0.f), 1.f) * a + bb;
      const float sl1 = fminf(fmaxf(f1, 0.f), 1.f) * a + bb;
      const float om = 1.f - g[j];
      s[j] = om * om * sl0 + g[j] * g[j] * sl1;
      si_out[((size_t)n * 4 + j) * HW + pp] = s[j];
    }
    const us4 zz = {0, 0, 0, 0};
    o.lo = pack4(s[0], s[1], s[2], s[3]);
    o.hi = zz;
    *(us8*)(dbase + 12 * 2048) = o;
    // groups 13-15: zeros
    o.lo = zz;
#pragma unroll
    for (int cg = 13; cg < 16; ++cg) *(us8*)(dbase + cg * 2048) = o;
  }
}

extern "C" void kernel_launch(void* const* d_in, const int* in_sizes, int n_in,
                              void* d_out, int out_size, void* d_ws, size_t ws_size,
                              hipStream_t stream) {
  (void)in_sizes; (void)n_in; (void)out_size; (void)ws_size;
  const float* ft0 = (const float*)d_in[0];
  const float* ft1 = (const float*)d_in[1];
  const float* gup = (const float*)d_in[2];
  const float* dd  = (const float*)d_in[3];
  const float* ca  = (const float*)d_in[4];
  const float* cb  = (const float*)d_in[5];
  const float* fw1 = (const float*)d_in[6];  const float* fb1 = (const float*)d_in[7];
  const float* fw2 = (const float*)d_in[8];  const float* fb2 = (const float*)d_in[9];
  const float* fw3 = (const float*)d_in[10]; const float* fb3 = (const float*)d_in[11];
  const float* dw1 = (const float*)d_in[12]; const float* db1 = (const float*)d_in[13];
  const float* dw2 = (const float*)d_in[14]; const float* db2 = (const float*)d_in[15];
  const float* dw3 = (const float*)d_in[16]; const float* db3 = (const float*)d_in[17];

  float* out = (float*)d_out;
  float* fo_out = out;                               // fusion_out  4*64*HW
  float* do_out = out + (size_t)4 * 64 * HW;         // denoise_out 4*64*HW
  float* ga_out = out + (size_t)8 * 64 * HW;         // gamma       4*4*HW
  float* si_out = ga_out + (size_t)4 * 4 * HW;       // sigma       4*4*HW

  char* ws = (char*)d_ws;
  u16* WR1 = (u16*)(ws);
  u16* WR2 = (u16*)(ws + 36864);
  u16* WR3 = (u16*)(ws + 110592);
  u16* WD1 = (u16*)(ws + 129024);
  u16* WD2 = (u16*)(ws + 276480);
  u16* WD3 = (u16*)(ws + 350208);
  u16* ZROW = (u16*)(ws + 425984);                   // 64 KB zeros
  u16* FIN = (u16*)(ws + (1 << 20));                 // 16 MB
  u16* H1  = (u16*)(ws + 17825792);                  // 32 MB
  u16* H2  = (u16*)(ws + 51380224);                  // 32 MB
  u16* DIN = (u16*)do_out;                           // 64 MB, dead until dconv3

  dim3 blk(256);
  // merged: 6 weight reorders + ZROW zero + fusion_in in one launch (506880 threads)
  prep_k<<<1980, blk, 0, stream>>>(fw1, fw2, fw3, dw1, dw2, dw3,
                                   WR1, WR2, WR3, WD1, WD2, WD3, ZROW,
                                   ft0, ft1, gup, ca, cb, FIN);

  dim3 cblk(512);
  conv3_k<32, 2, 0, 2><<<1024, cblk, 0, stream>>>(FIN, WR1, fb1, ZROW, H1, nullptr,
      nullptr, nullptr, nullptr, nullptr, nullptr, nullptr, nullptr, nullptr);
  conv3_k<64, 2, 0, 2><<<1024, cblk, 0, stream>>>(H1, WR2, fb2, ZROW, H2, nullptr,
      nullptr, nullptr, nullptr, nullptr, nullptr, nullptr, nullptr, nullptr);
  // gamma conv with fused fusion_post: writes gamma, fusion_out, sigma, DIN
  conv3_k<64, 1, 2, 1><<<512, cblk, 0, stream>>>(H2, WR3, fb3, ZROW, nullptr, ga_out,
      ft0, ft1, dd, ca, cb, fo_out, si_out, DIN);
  conv3_k<128, 2, 0, 2><<<1024, cblk, 0, stream>>>(DIN, WD1, db1, ZROW, H1, nullptr,
      nullptr, nullptr, nullptr, nullptr, nullptr, nullptr, nullptr, nullptr);
  conv3_k<64, 2, 0, 2><<<1024, cblk, 0, stream>>>(H1, WD2, db2, ZROW, H2, nullptr,
      nullptr, nullptr, nullptr, nullptr, nullptr, nullptr, nullptr, nullptr);
  conv3_k<64, 2, 1, 2><<<1024, cblk, 0, stream>>>(H2, WD3, db3, ZROW, nullptr, do_out,
      nullptr, nullptr, nullptr, nullptr, nullptr, nullptr, nullptr, nullptr);
}